// Round 1
// baseline (703.560 us; speedup 1.0000x reference)
//
#include <hip/hip_runtime.h>
#include <stdint.h>

// Problem constants (B=2, L=2048 -> T=4096)
#define T_TOK 4096
#define D_DIM 1024
#define H_DIM 512
#define E_NUM 16
#define S_DIM 2048

typedef __attribute__((ext_vector_type(8))) __bf16 bf16x8;
typedef __attribute__((ext_vector_type(4))) float f32x4;

__device__ __forceinline__ uint16_t f2bf(float f) {
  uint32_t u = __float_as_uint(f);
  u += 0x7fffu + ((u >> 16) & 1u);   // round-to-nearest-even
  return (uint16_t)(u >> 16);
}

__device__ __forceinline__ void gl_lds16(const void* g, void* l) {
  __builtin_amdgcn_global_load_lds(
      (const __attribute__((address_space(1))) void*)g,
      (__attribute__((address_space(3))) void*)l, 16, 0, 0);
}

__device__ __forceinline__ float silu_f(float v) {
  return v / (1.f + __expf(-v));
}

// ---------------- fp32 -> bf16 cast ----------------
__global__ void k_cast(const float* __restrict__ in, uint16_t* __restrict__ out, int n4) {
  int i = blockIdx.x * 256 + threadIdx.x;
  if (i >= n4) return;
  float4 v = ((const float4*)in)[i];
  ushort4 o;
  o.x = f2bf(v.x); o.y = f2bf(v.y); o.z = f2bf(v.z); o.w = f2bf(v.w);
  ((ushort4*)out)[i] = o;
}

// ---------------- router: logits (fp32), top-2, softmax, counts ----------------
__global__ void k_zero_counts(int* counts) {
  if (threadIdx.x < E_NUM) counts[threadIdx.x] = 0;
}

__global__ void k_router(const float* __restrict__ x, const float* __restrict__ gw,
                         int* __restrict__ top_idx, float* __restrict__ top_w,
                         int* __restrict__ counts) {
  __shared__ float slog[4][E_NUM];
  const int wid = threadIdx.x >> 6, lane = threadIdx.x & 63;
  const int t = blockIdx.x * 4 + wid;
  float xr[16];
#pragma unroll
  for (int j = 0; j < 16; j++) xr[j] = x[t * D_DIM + lane + 64 * j];
  for (int e = 0; e < E_NUM; e++) {
    const float* g = gw + e * D_DIM;
    float acc = 0.f;
#pragma unroll
    for (int j = 0; j < 16; j++) acc += xr[j] * g[lane + 64 * j];
#pragma unroll
    for (int off = 32; off > 0; off >>= 1) acc += __shfl_xor(acc, off, 64);
    if (lane == 0) slog[wid][e] = acc;
  }
  if (lane == 0) {
    float best = -1e30f; int bi = 0;
    for (int e = 0; e < E_NUM; e++) { float v = slog[wid][e]; if (v > best) { best = v; bi = e; } }
    float best2 = -1e30f; int bi2 = 0;
    for (int e = 0; e < E_NUM; e++) { if (e == bi) continue; float v = slog[wid][e]; if (v > best2) { best2 = v; bi2 = e; } }
    float w0 = 1.f / (1.f + __expf(best2 - best));
    top_idx[t * 2] = bi; top_idx[t * 2 + 1] = bi2;
    top_w[t * 2] = w0;  top_w[t * 2 + 1] = 1.f - w0;
    atomicAdd(&counts[bi], 1);
    atomicAdd(&counts[bi2], 1);
  }
}

__global__ void k_offsets(const int* __restrict__ counts, int* __restrict__ offsets,
                          int* __restrict__ cursor) {
  if (threadIdx.x == 0) {
    int s = 0;
    for (int e = 0; e < E_NUM; e++) { offsets[e] = s; cursor[e] = s; s += counts[e]; }
    offsets[E_NUM] = s;
  }
}

__global__ void k_fill(const int* __restrict__ top_idx, const float* __restrict__ top_w,
                       int* __restrict__ cursor, int* __restrict__ slot_token,
                       float* __restrict__ slot_w) {
  int id = blockIdx.x * 256 + threadIdx.x;  // 2*T entries
  if (id >= 2 * T_TOK) return;
  int t = id >> 1;
  int e = top_idx[id];
  int slot = atomicAdd(&cursor[e], 1);
  slot_token[slot] = t;
  slot_w[slot] = top_w[id];
}

// ---------------- GEMM core helpers ----------------
// LDS tiles: [128 rows][32 cols] bf16, row-major (K contiguous). No padding
// (global_load_lds requires contiguous lane order). Frags: A row = lane&15,
// k = (lane>>4)*8 + j (ds_read_b128). C/D: col = lane&15, row = (lane>>4)*4+r.

// ---------------- G1: dual GEMM, epilogue silu(a1)*a2 -> Hs bf16 ----------------
__global__ __launch_bounds__(256) void k_dual_gemm_silu(
    const uint16_t* __restrict__ xb, const uint16_t* __restrict__ b1,
    const uint16_t* __restrict__ b2, uint16_t* __restrict__ hs) {
  __shared__ uint16_t sA[128 * 32], sB1[128 * 32], sB2[128 * 32];
  const int tid = threadIdx.x, lane = tid & 63, wid = tid >> 6;
  const int wm = wid >> 1, wn = wid & 1;
  const int bm0 = blockIdx.x * 128, bn0 = blockIdx.y * 128;

  f32x4 acc1[4][4], acc2[4][4];
#pragma unroll
  for (int i = 0; i < 4; i++)
#pragma unroll
    for (int j = 0; j < 4; j++) {
      acc1[i][j] = (f32x4){0.f, 0.f, 0.f, 0.f};
      acc2[i][j] = (f32x4){0.f, 0.f, 0.f, 0.f};
    }

  const int row0 = tid >> 2, col8 = (tid & 3) * 8;
  const uint16_t* ga0 = xb + (size_t)(bm0 + row0) * D_DIM + col8;
  const uint16_t* ga1 = ga0 + 64 * D_DIM;
  const uint16_t* gb10 = b1 + (size_t)(bn0 + row0) * D_DIM + col8;
  const uint16_t* gb11 = gb10 + 64 * D_DIM;
  const uint16_t* gb20 = b2 + (size_t)(bn0 + row0) * D_DIM + col8;
  const uint16_t* gb21 = gb20 + 64 * D_DIM;
  uint16_t* lA0 = sA + wid * 512;  uint16_t* lA1 = sA + 2048 + wid * 512;
  uint16_t* lB10 = sB1 + wid * 512; uint16_t* lB11 = sB1 + 2048 + wid * 512;
  uint16_t* lB20 = sB2 + wid * 512; uint16_t* lB21 = sB2 + 2048 + wid * 512;

  const int r = lane & 15, q = lane >> 4;
  for (int kt = 0; kt < D_DIM; kt += 32) {
    gl_lds16(ga0, lA0);  gl_lds16(ga1, lA1);
    gl_lds16(gb10, lB10); gl_lds16(gb11, lB11);
    gl_lds16(gb20, lB20); gl_lds16(gb21, lB21);
    ga0 += 32; ga1 += 32; gb10 += 32; gb11 += 32; gb20 += 32; gb21 += 32;
    __syncthreads();
    bf16x8 a[4];
#pragma unroll
    for (int i = 0; i < 4; i++)
      a[i] = *(const bf16x8*)(sA + (wm * 64 + i * 16 + r) * 32 + q * 8);
#pragma unroll
    for (int j = 0; j < 4; j++) {
      bf16x8 b = *(const bf16x8*)(sB1 + (wn * 64 + j * 16 + r) * 32 + q * 8);
#pragma unroll
      for (int i = 0; i < 4; i++)
        acc1[i][j] = __builtin_amdgcn_mfma_f32_16x16x32_bf16(a[i], b, acc1[i][j], 0, 0, 0);
    }
#pragma unroll
    for (int j = 0; j < 4; j++) {
      bf16x8 b = *(const bf16x8*)(sB2 + (wn * 64 + j * 16 + r) * 32 + q * 8);
#pragma unroll
      for (int i = 0; i < 4; i++)
        acc2[i][j] = __builtin_amdgcn_mfma_f32_16x16x32_bf16(a[i], b, acc2[i][j], 0, 0, 0);
    }
    __syncthreads();
  }
#pragma unroll
  for (int i = 0; i < 4; i++)
#pragma unroll
    for (int j = 0; j < 4; j++)
#pragma unroll
      for (int rr = 0; rr < 4; rr++) {
        int row = bm0 + wm * 64 + i * 16 + q * 4 + rr;
        int col = bn0 + wn * 64 + j * 16 + r;
        float aa = acc1[i][j][rr], bb = acc2[i][j][rr];
        hs[(size_t)row * S_DIM + col] = f2bf(silu_f(aa) * bb);
      }
}

// ---------------- G2: shared = Hs @ sfc3^T -> fp32 stores to out ----------------
__global__ __launch_bounds__(256) void k_gemm_shared_out(
    const uint16_t* __restrict__ hsb, const uint16_t* __restrict__ b,
    float* __restrict__ out) {
  __shared__ uint16_t sA[128 * 32], sB[128 * 32];
  const int tid = threadIdx.x, lane = tid & 63, wid = tid >> 6;
  const int wm = wid >> 1, wn = wid & 1;
  const int bm0 = blockIdx.x * 128, bn0 = blockIdx.y * 128;
  f32x4 acc[4][4];
#pragma unroll
  for (int i = 0; i < 4; i++)
#pragma unroll
    for (int j = 0; j < 4; j++) acc[i][j] = (f32x4){0.f, 0.f, 0.f, 0.f};

  const int row0 = tid >> 2, col8 = (tid & 3) * 8;
  const uint16_t* ga0 = hsb + (size_t)(bm0 + row0) * S_DIM + col8;
  const uint16_t* ga1 = ga0 + (size_t)64 * S_DIM;
  const uint16_t* gb0 = b + (size_t)(bn0 + row0) * S_DIM + col8;
  const uint16_t* gb1 = gb0 + (size_t)64 * S_DIM;
  uint16_t* lA0 = sA + wid * 512; uint16_t* lA1 = sA + 2048 + wid * 512;
  uint16_t* lB0 = sB + wid * 512; uint16_t* lB1 = sB + 2048 + wid * 512;
  const int r = lane & 15, q = lane >> 4;
  for (int kt = 0; kt < S_DIM; kt += 32) {
    gl_lds16(ga0, lA0); gl_lds16(ga1, lA1);
    gl_lds16(gb0, lB0); gl_lds16(gb1, lB1);
    ga0 += 32; ga1 += 32; gb0 += 32; gb1 += 32;
    __syncthreads();
    bf16x8 a[4], bb[4];
#pragma unroll
    for (int i = 0; i < 4; i++)
      a[i] = *(const bf16x8*)(sA + (wm * 64 + i * 16 + r) * 32 + q * 8);
#pragma unroll
    for (int j = 0; j < 4; j++)
      bb[j] = *(const bf16x8*)(sB + (wn * 64 + j * 16 + r) * 32 + q * 8);
#pragma unroll
    for (int i = 0; i < 4; i++)
#pragma unroll
      for (int j = 0; j < 4; j++)
        acc[i][j] = __builtin_amdgcn_mfma_f32_16x16x32_bf16(a[i], bb[j], acc[i][j], 0, 0, 0);
    __syncthreads();
  }
#pragma unroll
  for (int i = 0; i < 4; i++)
#pragma unroll
    for (int j = 0; j < 4; j++)
#pragma unroll
      for (int rr = 0; rr < 4; rr++) {
        int row = bm0 + wm * 64 + i * 16 + q * 4 + rr;
        int col = bn0 + wn * 64 + j * 16 + r;
        out[(size_t)row * D_DIM + col] = acc[i][j][rr];
      }
}

// ---------------- M1: grouped h = silu(Xg @ w1[e]^T) -> bf16 ----------------
__global__ __launch_bounds__(256) void k_moe1(
    const uint16_t* __restrict__ xb, const uint16_t* __restrict__ w1b,
    const int* __restrict__ offsets, const int* __restrict__ slot_token,
    uint16_t* __restrict__ hbuf) {
  const int e = blockIdx.z;
  const int base = offsets[e];
  const int ne = offsets[e + 1] - base;
  const int m0 = blockIdx.x * 128;
  if (m0 >= ne) return;
  const int n0 = blockIdx.y * 128;  // over H=512
  __shared__ uint16_t sA[128 * 32], sB[128 * 32];
  const int tid = threadIdx.x, lane = tid & 63, wid = tid >> 6;
  const int wm = wid >> 1, wn = wid & 1;
  f32x4 acc[4][4];
#pragma unroll
  for (int i = 0; i < 4; i++)
#pragma unroll
    for (int j = 0; j < 4; j++) acc[i][j] = (f32x4){0.f, 0.f, 0.f, 0.f};

  const int row0 = tid >> 2, col8 = (tid & 3) * 8;
  const int e0 = min(m0 + row0, ne - 1);
  const int e1 = min(m0 + row0 + 64, ne - 1);
  const uint16_t* ga0 = xb + (size_t)slot_token[base + e0] * D_DIM + col8;
  const uint16_t* ga1 = xb + (size_t)slot_token[base + e1] * D_DIM + col8;
  const uint16_t* wbase = w1b + (size_t)e * H_DIM * D_DIM;
  const uint16_t* gb0 = wbase + (size_t)(n0 + row0) * D_DIM + col8;
  const uint16_t* gb1 = gb0 + 64 * D_DIM;
  uint16_t* lA0 = sA + wid * 512; uint16_t* lA1 = sA + 2048 + wid * 512;
  uint16_t* lB0 = sB + wid * 512; uint16_t* lB1 = sB + 2048 + wid * 512;
  const int r = lane & 15, q = lane >> 4;
  for (int kt = 0; kt < D_DIM; kt += 32) {
    gl_lds16(ga0, lA0); gl_lds16(ga1, lA1);
    gl_lds16(gb0, lB0); gl_lds16(gb1, lB1);
    ga0 += 32; ga1 += 32; gb0 += 32; gb1 += 32;
    __syncthreads();
    bf16x8 a[4], bb[4];
#pragma unroll
    for (int i = 0; i < 4; i++)
      a[i] = *(const bf16x8*)(sA + (wm * 64 + i * 16 + r) * 32 + q * 8);
#pragma unroll
    for (int j = 0; j < 4; j++)
      bb[j] = *(const bf16x8*)(sB + (wn * 64 + j * 16 + r) * 32 + q * 8);
#pragma unroll
    for (int i = 0; i < 4; i++)
#pragma unroll
      for (int j = 0; j < 4; j++)
        acc[i][j] = __builtin_amdgcn_mfma_f32_16x16x32_bf16(a[i], bb[j], acc[i][j], 0, 0, 0);
    __syncthreads();
  }
#pragma unroll
  for (int i = 0; i < 4; i++)
#pragma unroll
    for (int j = 0; j < 4; j++)
#pragma unroll
      for (int rr = 0; rr < 4; rr++) {
        int ent = m0 + wm * 64 + i * 16 + q * 4 + rr;
        if (ent < ne) {
          int col = n0 + wn * 64 + j * 16 + r;
          hbuf[(size_t)(base + ent) * H_DIM + col] = f2bf(silu_f(acc[i][j][rr]));
        }
      }
}

// ---------------- M2: moe = h @ w2[e]^T, scatter atomicAdd(w * val) ----------------
__global__ __launch_bounds__(256) void k_moe2(
    const uint16_t* __restrict__ hbuf, const uint16_t* __restrict__ w2b,
    const int* __restrict__ offsets, const int* __restrict__ slot_token,
    const float* __restrict__ slot_w, float* __restrict__ out) {
  const int e = blockIdx.z;
  const int base = offsets[e];
  const int ne = offsets[e + 1] - base;
  const int m0 = blockIdx.x * 128;
  if (m0 >= ne) return;
  const int n0 = blockIdx.y * 128;  // over D=1024
  __shared__ uint16_t sA[128 * 32], sB[128 * 32];
  const int tid = threadIdx.x, lane = tid & 63, wid = tid >> 6;
  const int wm = wid >> 1, wn = wid & 1;
  f32x4 acc[4][4];
#pragma unroll
  for (int i = 0; i < 4; i++)
#pragma unroll
    for (int j = 0; j < 4; j++) acc[i][j] = (f32x4){0.f, 0.f, 0.f, 0.f};

  const int row0 = tid >> 2, col8 = (tid & 3) * 8;
  const int e0 = min(m0 + row0, ne - 1);
  const int e1 = min(m0 + row0 + 64, ne - 1);
  const uint16_t* ga0 = hbuf + (size_t)(base + e0) * H_DIM + col8;
  const uint16_t* ga1 = hbuf + (size_t)(base + e1) * H_DIM + col8;
  const uint16_t* wbase = w2b + (size_t)e * D_DIM * H_DIM;
  const uint16_t* gb0 = wbase + (size_t)(n0 + row0) * H_DIM + col8;
  const uint16_t* gb1 = gb0 + 64 * H_DIM;
  uint16_t* lA0 = sA + wid * 512; uint16_t* lA1 = sA + 2048 + wid * 512;
  uint16_t* lB0 = sB + wid * 512; uint16_t* lB1 = sB + 2048 + wid * 512;
  const int r = lane & 15, q = lane >> 4;
  for (int kt = 0; kt < H_DIM; kt += 32) {
    gl_lds16(ga0, lA0); gl_lds16(ga1, lA1);
    gl_lds16(gb0, lB0); gl_lds16(gb1, lB1);
    ga0 += 32; ga1 += 32; gb0 += 32; gb1 += 32;
    __syncthreads();
    bf16x8 a[4], bb[4];
#pragma unroll
    for (int i = 0; i < 4; i++)
      a[i] = *(const bf16x8*)(sA + (wm * 64 + i * 16 + r) * 32 + q * 8);
#pragma unroll
    for (int j = 0; j < 4; j++)
      bb[j] = *(const bf16x8*)(sB + (wn * 64 + j * 16 + r) * 32 + q * 8);
#pragma unroll
    for (int i = 0; i < 4; i++)
#pragma unroll
      for (int j = 0; j < 4; j++)
        acc[i][j] = __builtin_amdgcn_mfma_f32_16x16x32_bf16(a[i], bb[j], acc[i][j], 0, 0, 0);
    __syncthreads();
  }
#pragma unroll
  for (int i = 0; i < 4; i++)
#pragma unroll
    for (int j = 0; j < 4; j++)
#pragma unroll
      for (int rr = 0; rr < 4; rr++) {
        int ent = m0 + wm * 64 + i * 16 + q * 4 + rr;
        if (ent < ne) {
          int t = slot_token[base + ent];
          float w = slot_w[base + ent];
          int col = n0 + wn * 64 + j * 16 + r;
          atomicAdd(&out[(size_t)t * D_DIM + col], w * acc[i][j][rr]);
        }
      }
}

// ---------------- launch ----------------
extern "C" void kernel_launch(void* const* d_in, const int* in_sizes, int n_in,
                              void* d_out, int out_size, void* d_ws, size_t ws_size,
                              hipStream_t stream) {
  const float* x     = (const float*)d_in[0];
  const float* gatew = (const float*)d_in[1];
  const float* w1    = (const float*)d_in[2];
  const float* w2    = (const float*)d_in[3];
  const float* sfc1  = (const float*)d_in[4];
  const float* sfc2  = (const float*)d_in[5];
  const float* sfc3  = (const float*)d_in[6];
  float* out = (float*)d_out;

  uint8_t* ws = (uint8_t*)d_ws;
  size_t off = 0;
  auto alloc = [&](size_t bytes) {
    void* p = ws + off;
    off = (off + bytes + 255) & ~(size_t)255;
    return p;
  };
  uint16_t* xb    = (uint16_t*)alloc((size_t)T_TOK * D_DIM * 2);
  uint16_t* sfc1b = (uint16_t*)alloc((size_t)S_DIM * D_DIM * 2);
  uint16_t* sfc2b = (uint16_t*)alloc((size_t)S_DIM * D_DIM * 2);
  uint16_t* sfc3b = (uint16_t*)alloc((size_t)D_DIM * S_DIM * 2);
  uint16_t* w1b   = (uint16_t*)alloc((size_t)E_NUM * H_DIM * D_DIM * 2);
  uint16_t* w2b   = (uint16_t*)alloc((size_t)E_NUM * D_DIM * H_DIM * 2);
  uint16_t* hsb   = (uint16_t*)alloc((size_t)T_TOK * S_DIM * 2);
  uint16_t* hbuf  = (uint16_t*)alloc((size_t)2 * T_TOK * H_DIM * 2);
  int*   top_idx  = (int*)alloc((size_t)T_TOK * 2 * 4);
  float* top_w    = (float*)alloc((size_t)T_TOK * 2 * 4);
  int*   counts   = (int*)alloc(E_NUM * 4);
  int*   offsets  = (int*)alloc((E_NUM + 1) * 4);
  int*   cursor   = (int*)alloc(E_NUM * 4);
  int*   slot_token = (int*)alloc((size_t)2 * T_TOK * 4);
  float* slot_w   = (float*)alloc((size_t)2 * T_TOK * 4);

  // 1. casts
  {
    int n4;
    n4 = T_TOK * D_DIM / 4;  k_cast<<<(n4 + 255) / 256, 256, 0, stream>>>(x, xb, n4);
    n4 = S_DIM * D_DIM / 4;  k_cast<<<(n4 + 255) / 256, 256, 0, stream>>>(sfc1, sfc1b, n4);
    n4 = S_DIM * D_DIM / 4;  k_cast<<<(n4 + 255) / 256, 256, 0, stream>>>(sfc2, sfc2b, n4);
    n4 = D_DIM * S_DIM / 4;  k_cast<<<(n4 + 255) / 256, 256, 0, stream>>>(sfc3, sfc3b, n4);
    n4 = E_NUM * H_DIM * D_DIM / 4; k_cast<<<(n4 + 255) / 256, 256, 0, stream>>>(w1, w1b, n4);
    n4 = E_NUM * D_DIM * H_DIM / 4; k_cast<<<(n4 + 255) / 256, 256, 0, stream>>>(w2, w2b, n4);
  }
  // 2. router
  k_zero_counts<<<1, 64, 0, stream>>>(counts);
  k_router<<<T_TOK / 4, 256, 0, stream>>>(x, gatew, top_idx, top_w, counts);
  k_offsets<<<1, 64, 0, stream>>>(counts, offsets, cursor);
  k_fill<<<(2 * T_TOK + 255) / 256, 256, 0, stream>>>(top_idx, top_w, cursor, slot_token, slot_w);
  // 3. shared expert
  k_dual_gemm_silu<<<dim3(T_TOK / 128, S_DIM / 128), 256, 0, stream>>>(xb, sfc1b, sfc2b, hsb);
  k_gemm_shared_out<<<dim3(T_TOK / 128, D_DIM / 128), 256, 0, stream>>>(hsb, sfc3b, out);
  // 4. MoE grouped
  k_moe1<<<dim3(T_TOK / 128, H_DIM / 128, E_NUM), 256, 0, stream>>>(xb, w1b, offsets, slot_token, hbuf);
  k_moe2<<<dim3(T_TOK / 128, D_DIM / 128, E_NUM), 256, 0, stream>>>(hbuf, w2b, offsets, slot_token, slot_w, out);
}

// Round 2
// 592.601 us; speedup vs baseline: 1.1872x; 1.1872x over previous
//
#include <hip/hip_runtime.h>
#include <stdint.h>

// Problem constants (B=2, L=2048 -> T=4096)
#define T_TOK 4096
#define D_DIM 1024
#define H_DIM 512
#define E_NUM 16
#define S_DIM 2048

typedef __attribute__((ext_vector_type(8))) __bf16 bf16x8;
typedef __attribute__((ext_vector_type(4))) float f32x4;

__device__ __forceinline__ uint16_t f2bf(float f) {
  uint32_t u = __float_as_uint(f);
  u += 0x7fffu + ((u >> 16) & 1u);   // round-to-nearest-even
  return (uint16_t)(u >> 16);
}

__device__ __forceinline__ void gl_lds16(const void* g, void* l) {
  __builtin_amdgcn_global_load_lds(
      (const __attribute__((address_space(1))) void*)g,
      (__attribute__((address_space(3))) void*)l, 16, 0, 0);
}

__device__ __forceinline__ float silu_f(float v) {
  return v / (1.f + __expf(-v));
}

// ---------------- fp32 -> bf16 cast ----------------
__global__ void k_cast(const float* __restrict__ in, uint16_t* __restrict__ out, int n4) {
  int i = blockIdx.x * 256 + threadIdx.x;
  if (i >= n4) return;
  float4 v = ((const float4*)in)[i];
  ushort4 o;
  o.x = f2bf(v.x); o.y = f2bf(v.y); o.z = f2bf(v.z); o.w = f2bf(v.w);
  ((ushort4*)out)[i] = o;
}

// ---------------- router: logits (fp32), top-2, softmax, counts ----------------
__global__ void k_zero_counts(int* counts) {
  if (threadIdx.x < E_NUM) counts[threadIdx.x] = 0;
}

__global__ void k_router(const float* __restrict__ x, const float* __restrict__ gw,
                         int* __restrict__ top_idx, float* __restrict__ top_w,
                         int* __restrict__ counts) {
  __shared__ float slog[4][E_NUM];
  const int wid = threadIdx.x >> 6, lane = threadIdx.x & 63;
  const int t = blockIdx.x * 4 + wid;
  float xr[16];
#pragma unroll
  for (int j = 0; j < 16; j++) xr[j] = x[t * D_DIM + lane + 64 * j];
  for (int e = 0; e < E_NUM; e++) {
    const float* g = gw + e * D_DIM;
    float acc = 0.f;
#pragma unroll
    for (int j = 0; j < 16; j++) acc += xr[j] * g[lane + 64 * j];
#pragma unroll
    for (int off = 32; off > 0; off >>= 1) acc += __shfl_xor(acc, off, 64);
    if (lane == 0) slog[wid][e] = acc;
  }
  if (lane == 0) {
    float best = -1e30f; int bi = 0;
    for (int e = 0; e < E_NUM; e++) { float v = slog[wid][e]; if (v > best) { best = v; bi = e; } }
    float best2 = -1e30f; int bi2 = 0;
    for (int e = 0; e < E_NUM; e++) { if (e == bi) continue; float v = slog[wid][e]; if (v > best2) { best2 = v; bi2 = e; } }
    float w0 = 1.f / (1.f + __expf(best2 - best));
    top_idx[t * 2] = bi; top_idx[t * 2 + 1] = bi2;
    top_w[t * 2] = w0;  top_w[t * 2 + 1] = 1.f - w0;
    atomicAdd(&counts[bi], 1);
    atomicAdd(&counts[bi2], 1);
  }
}

__global__ void k_offsets(const int* __restrict__ counts, int* __restrict__ offsets,
                          int* __restrict__ cursor) {
  if (threadIdx.x == 0) {
    int s = 0;
    for (int e = 0; e < E_NUM; e++) { offsets[e] = s; cursor[e] = s; s += counts[e]; }
    offsets[E_NUM] = s;
  }
}

__global__ void k_fill(const int* __restrict__ top_idx, const float* __restrict__ top_w,
                       int* __restrict__ cursor, int* __restrict__ slot_token,
                       float* __restrict__ slot_w, int* __restrict__ slot_of) {
  int id = blockIdx.x * 256 + threadIdx.x;  // 2*T entries
  if (id >= 2 * T_TOK) return;
  int t = id >> 1;
  int e = top_idx[id];
  int slot = atomicAdd(&cursor[e], 1);
  slot_token[slot] = t;
  slot_w[slot] = top_w[id];
  slot_of[id] = slot;
}

// ---------------- GEMM core helpers ----------------
// LDS tiles: [128 rows][32 cols] bf16, row-major (K contiguous). No padding
// (global_load_lds requires contiguous lane order). Frags: A row = lane&15,
// k = (lane>>4)*8 + j (ds_read_b128). C/D: col = lane&15, row = (lane>>4)*4+r.

// ---------------- G1: dual GEMM, epilogue silu(a1)*a2 -> Hs bf16 ----------------
__global__ __launch_bounds__(256) void k_dual_gemm_silu(
    const uint16_t* __restrict__ xb, const uint16_t* __restrict__ b1,
    const uint16_t* __restrict__ b2, uint16_t* __restrict__ hs) {
  __shared__ uint16_t sA[128 * 32], sB1[128 * 32], sB2[128 * 32];
  const int tid = threadIdx.x, lane = tid & 63, wid = tid >> 6;
  const int wm = wid >> 1, wn = wid & 1;
  const int bm0 = blockIdx.x * 128, bn0 = blockIdx.y * 128;

  f32x4 acc1[4][4], acc2[4][4];
#pragma unroll
  for (int i = 0; i < 4; i++)
#pragma unroll
    for (int j = 0; j < 4; j++) {
      acc1[i][j] = (f32x4){0.f, 0.f, 0.f, 0.f};
      acc2[i][j] = (f32x4){0.f, 0.f, 0.f, 0.f};
    }

  const int row0 = tid >> 2, col8 = (tid & 3) * 8;
  const uint16_t* ga0 = xb + (size_t)(bm0 + row0) * D_DIM + col8;
  const uint16_t* ga1 = ga0 + 64 * D_DIM;
  const uint16_t* gb10 = b1 + (size_t)(bn0 + row0) * D_DIM + col8;
  const uint16_t* gb11 = gb10 + 64 * D_DIM;
  const uint16_t* gb20 = b2 + (size_t)(bn0 + row0) * D_DIM + col8;
  const uint16_t* gb21 = gb20 + 64 * D_DIM;
  uint16_t* lA0 = sA + wid * 512;  uint16_t* lA1 = sA + 2048 + wid * 512;
  uint16_t* lB10 = sB1 + wid * 512; uint16_t* lB11 = sB1 + 2048 + wid * 512;
  uint16_t* lB20 = sB2 + wid * 512; uint16_t* lB21 = sB2 + 2048 + wid * 512;

  const int r = lane & 15, q = lane >> 4;
  for (int kt = 0; kt < D_DIM; kt += 32) {
    gl_lds16(ga0, lA0);  gl_lds16(ga1, lA1);
    gl_lds16(gb10, lB10); gl_lds16(gb11, lB11);
    gl_lds16(gb20, lB20); gl_lds16(gb21, lB21);
    ga0 += 32; ga1 += 32; gb10 += 32; gb11 += 32; gb20 += 32; gb21 += 32;
    __syncthreads();
    bf16x8 a[4];
#pragma unroll
    for (int i = 0; i < 4; i++)
      a[i] = *(const bf16x8*)(sA + (wm * 64 + i * 16 + r) * 32 + q * 8);
#pragma unroll
    for (int j = 0; j < 4; j++) {
      bf16x8 b = *(const bf16x8*)(sB1 + (wn * 64 + j * 16 + r) * 32 + q * 8);
#pragma unroll
      for (int i = 0; i < 4; i++)
        acc1[i][j] = __builtin_amdgcn_mfma_f32_16x16x32_bf16(a[i], b, acc1[i][j], 0, 0, 0);
    }
#pragma unroll
    for (int j = 0; j < 4; j++) {
      bf16x8 b = *(const bf16x8*)(sB2 + (wn * 64 + j * 16 + r) * 32 + q * 8);
#pragma unroll
      for (int i = 0; i < 4; i++)
        acc2[i][j] = __builtin_amdgcn_mfma_f32_16x16x32_bf16(a[i], b, acc2[i][j], 0, 0, 0);
    }
    __syncthreads();
  }
#pragma unroll
  for (int i = 0; i < 4; i++)
#pragma unroll
    for (int j = 0; j < 4; j++)
#pragma unroll
      for (int rr = 0; rr < 4; rr++) {
        int row = bm0 + wm * 64 + i * 16 + q * 4 + rr;
        int col = bn0 + wn * 64 + j * 16 + r;
        float aa = acc1[i][j][rr], bb = acc2[i][j][rr];
        hs[(size_t)row * S_DIM + col] = f2bf(silu_f(aa) * bb);
      }
}

// ---------------- G2: shared = Hs @ sfc3^T -> fp32 stores to out ----------------
__global__ __launch_bounds__(256) void k_gemm_shared_out(
    const uint16_t* __restrict__ hsb, const uint16_t* __restrict__ b,
    float* __restrict__ out) {
  __shared__ uint16_t sA[128 * 32], sB[128 * 32];
  const int tid = threadIdx.x, lane = tid & 63, wid = tid >> 6;
  const int wm = wid >> 1, wn = wid & 1;
  const int bm0 = blockIdx.x * 128, bn0 = blockIdx.y * 128;
  f32x4 acc[4][4];
#pragma unroll
  for (int i = 0; i < 4; i++)
#pragma unroll
    for (int j = 0; j < 4; j++) acc[i][j] = (f32x4){0.f, 0.f, 0.f, 0.f};

  const int row0 = tid >> 2, col8 = (tid & 3) * 8;
  const uint16_t* ga0 = hsb + (size_t)(bm0 + row0) * S_DIM + col8;
  const uint16_t* ga1 = ga0 + (size_t)64 * S_DIM;
  const uint16_t* gb0 = b + (size_t)(bn0 + row0) * S_DIM + col8;
  const uint16_t* gb1 = gb0 + (size_t)64 * S_DIM;
  uint16_t* lA0 = sA + wid * 512; uint16_t* lA1 = sA + 2048 + wid * 512;
  uint16_t* lB0 = sB + wid * 512; uint16_t* lB1 = sB + 2048 + wid * 512;
  const int r = lane & 15, q = lane >> 4;
  for (int kt = 0; kt < S_DIM; kt += 32) {
    gl_lds16(ga0, lA0); gl_lds16(ga1, lA1);
    gl_lds16(gb0, lB0); gl_lds16(gb1, lB1);
    ga0 += 32; ga1 += 32; gb0 += 32; gb1 += 32;
    __syncthreads();
    bf16x8 a[4], bb[4];
#pragma unroll
    for (int i = 0; i < 4; i++)
      a[i] = *(const bf16x8*)(sA + (wm * 64 + i * 16 + r) * 32 + q * 8);
#pragma unroll
    for (int j = 0; j < 4; j++)
      bb[j] = *(const bf16x8*)(sB + (wn * 64 + j * 16 + r) * 32 + q * 8);
#pragma unroll
    for (int i = 0; i < 4; i++)
#pragma unroll
      for (int j = 0; j < 4; j++)
        acc[i][j] = __builtin_amdgcn_mfma_f32_16x16x32_bf16(a[i], bb[j], acc[i][j], 0, 0, 0);
    __syncthreads();
  }
#pragma unroll
  for (int i = 0; i < 4; i++)
#pragma unroll
    for (int j = 0; j < 4; j++)
#pragma unroll
      for (int rr = 0; rr < 4; rr++) {
        int row = bm0 + wm * 64 + i * 16 + q * 4 + rr;
        int col = bn0 + wn * 64 + j * 16 + r;
        out[(size_t)row * D_DIM + col] = acc[i][j][rr];
      }
}

// ---------------- M1: grouped h = silu(Xg @ w1[e]^T) -> bf16 ----------------
__global__ __launch_bounds__(256) void k_moe1(
    const uint16_t* __restrict__ xb, const uint16_t* __restrict__ w1b,
    const int* __restrict__ offsets, const int* __restrict__ slot_token,
    uint16_t* __restrict__ hbuf) {
  const int e = blockIdx.z;
  const int base = offsets[e];
  const int ne = offsets[e + 1] - base;
  const int m0 = blockIdx.x * 128;
  if (m0 >= ne) return;
  const int n0 = blockIdx.y * 128;  // over H=512
  __shared__ uint16_t sA[128 * 32], sB[128 * 32];
  const int tid = threadIdx.x, lane = tid & 63, wid = tid >> 6;
  const int wm = wid >> 1, wn = wid & 1;
  f32x4 acc[4][4];
#pragma unroll
  for (int i = 0; i < 4; i++)
#pragma unroll
    for (int j = 0; j < 4; j++) acc[i][j] = (f32x4){0.f, 0.f, 0.f, 0.f};

  const int row0 = tid >> 2, col8 = (tid & 3) * 8;
  const int e0 = min(m0 + row0, ne - 1);
  const int e1 = min(m0 + row0 + 64, ne - 1);
  const uint16_t* ga0 = xb + (size_t)slot_token[base + e0] * D_DIM + col8;
  const uint16_t* ga1 = xb + (size_t)slot_token[base + e1] * D_DIM + col8;
  const uint16_t* wbase = w1b + (size_t)e * H_DIM * D_DIM;
  const uint16_t* gb0 = wbase + (size_t)(n0 + row0) * D_DIM + col8;
  const uint16_t* gb1 = gb0 + 64 * D_DIM;
  uint16_t* lA0 = sA + wid * 512; uint16_t* lA1 = sA + 2048 + wid * 512;
  uint16_t* lB0 = sB + wid * 512; uint16_t* lB1 = sB + 2048 + wid * 512;
  const int r = lane & 15, q = lane >> 4;
  for (int kt = 0; kt < D_DIM; kt += 32) {
    gl_lds16(ga0, lA0); gl_lds16(ga1, lA1);
    gl_lds16(gb0, lB0); gl_lds16(gb1, lB1);
    ga0 += 32; ga1 += 32; gb0 += 32; gb1 += 32;
    __syncthreads();
    bf16x8 a[4], bb[4];
#pragma unroll
    for (int i = 0; i < 4; i++)
      a[i] = *(const bf16x8*)(sA + (wm * 64 + i * 16 + r) * 32 + q * 8);
#pragma unroll
    for (int j = 0; j < 4; j++)
      bb[j] = *(const bf16x8*)(sB + (wn * 64 + j * 16 + r) * 32 + q * 8);
#pragma unroll
    for (int i = 0; i < 4; i++)
#pragma unroll
      for (int j = 0; j < 4; j++)
        acc[i][j] = __builtin_amdgcn_mfma_f32_16x16x32_bf16(a[i], bb[j], acc[i][j], 0, 0, 0);
    __syncthreads();
  }
#pragma unroll
  for (int i = 0; i < 4; i++)
#pragma unroll
    for (int j = 0; j < 4; j++)
#pragma unroll
      for (int rr = 0; rr < 4; rr++) {
        int ent = m0 + wm * 64 + i * 16 + q * 4 + rr;
        if (ent < ne) {
          int col = n0 + wn * 64 + j * 16 + r;
          hbuf[(size_t)(base + ent) * H_DIM + col] = f2bf(silu_f(acc[i][j][rr]));
        }
      }
}

// ---------------- M2: moe = h @ w2[e]^T, dense per-slot stores (NO atomics) ----------------
__global__ __launch_bounds__(256) void k_moe2(
    const uint16_t* __restrict__ hbuf, const uint16_t* __restrict__ w2b,
    const int* __restrict__ offsets, const int* __restrict__ slot_w_unused,
    const float* __restrict__ slot_w, float* __restrict__ slot_out) {
  const int e = blockIdx.z;
  const int base = offsets[e];
  const int ne = offsets[e + 1] - base;
  const int m0 = blockIdx.x * 128;
  if (m0 >= ne) return;
  const int n0 = blockIdx.y * 128;  // over D=1024
  __shared__ uint16_t sA[128 * 32], sB[128 * 32];
  const int tid = threadIdx.x, lane = tid & 63, wid = tid >> 6;
  const int wm = wid >> 1, wn = wid & 1;
  f32x4 acc[4][4];
#pragma unroll
  for (int i = 0; i < 4; i++)
#pragma unroll
    for (int j = 0; j < 4; j++) acc[i][j] = (f32x4){0.f, 0.f, 0.f, 0.f};

  const int row0 = tid >> 2, col8 = (tid & 3) * 8;
  const int e0 = min(m0 + row0, ne - 1);
  const int e1 = min(m0 + row0 + 64, ne - 1);
  const uint16_t* ga0 = hbuf + (size_t)(base + e0) * H_DIM + col8;
  const uint16_t* ga1 = hbuf + (size_t)(base + e1) * H_DIM + col8;
  const uint16_t* wbase = w2b + (size_t)e * D_DIM * H_DIM;
  const uint16_t* gb0 = wbase + (size_t)(n0 + row0) * H_DIM + col8;
  const uint16_t* gb1 = gb0 + 64 * H_DIM;
  uint16_t* lA0 = sA + wid * 512; uint16_t* lA1 = sA + 2048 + wid * 512;
  uint16_t* lB0 = sB + wid * 512; uint16_t* lB1 = sB + 2048 + wid * 512;
  const int r = lane & 15, q = lane >> 4;
  for (int kt = 0; kt < H_DIM; kt += 32) {
    gl_lds16(ga0, lA0); gl_lds16(ga1, lA1);
    gl_lds16(gb0, lB0); gl_lds16(gb1, lB1);
    ga0 += 32; ga1 += 32; gb0 += 32; gb1 += 32;
    __syncthreads();
    bf16x8 a[4], bb[4];
#pragma unroll
    for (int i = 0; i < 4; i++)
      a[i] = *(const bf16x8*)(sA + (wm * 64 + i * 16 + r) * 32 + q * 8);
#pragma unroll
    for (int j = 0; j < 4; j++)
      bb[j] = *(const bf16x8*)(sB + (wn * 64 + j * 16 + r) * 32 + q * 8);
#pragma unroll
    for (int i = 0; i < 4; i++)
#pragma unroll
      for (int j = 0; j < 4; j++)
        acc[i][j] = __builtin_amdgcn_mfma_f32_16x16x32_bf16(a[i], bb[j], acc[i][j], 0, 0, 0);
    __syncthreads();
  }
#pragma unroll
  for (int i = 0; i < 4; i++) {
    int ent_base = m0 + wm * 64 + i * 16 + q * 4;
#pragma unroll
    for (int rr = 0; rr < 4; rr++) {
      int ent = ent_base + rr;
      if (ent < ne) {
        float w = slot_w[base + ent];
        float* orow = slot_out + (size_t)(base + ent) * D_DIM;
#pragma unroll
        for (int j = 0; j < 4; j++) {
          int col = n0 + wn * 64 + j * 16 + r;
          orow[col] = w * acc[i][j][rr];
        }
      }
    }
  }
}

// ---------------- combine: out[t] += slot_out[slot0[t]] + slot_out[slot1[t]] ----------------
__global__ __launch_bounds__(256) void k_combine(
    const float* __restrict__ slot_out, const int* __restrict__ slot_of,
    float* __restrict__ out) {
  // one block handles one token's 1024 floats as 256 float4
  int t = blockIdx.x;
  int c = threadIdx.x;
  int s0 = slot_of[t * 2], s1 = slot_of[t * 2 + 1];
  float4 a = ((const float4*)(slot_out + (size_t)s0 * D_DIM))[c];
  float4 b = ((const float4*)(slot_out + (size_t)s1 * D_DIM))[c];
  float4* po = (float4*)(out + (size_t)t * D_DIM) + c;
  float4 o = *po;
  o.x += a.x + b.x; o.y += a.y + b.y; o.z += a.z + b.z; o.w += a.w + b.w;
  *po = o;
}

// ---------------- launch ----------------
extern "C" void kernel_launch(void* const* d_in, const int* in_sizes, int n_in,
                              void* d_out, int out_size, void* d_ws, size_t ws_size,
                              hipStream_t stream) {
  const float* x     = (const float*)d_in[0];
  const float* gatew = (const float*)d_in[1];
  const float* w1    = (const float*)d_in[2];
  const float* w2    = (const float*)d_in[3];
  const float* sfc1  = (const float*)d_in[4];
  const float* sfc2  = (const float*)d_in[5];
  const float* sfc3  = (const float*)d_in[6];
  float* out = (float*)d_out;

  uint8_t* ws = (uint8_t*)d_ws;
  size_t off = 0;
  auto alloc = [&](size_t bytes) {
    void* p = ws + off;
    off = (off + bytes + 255) & ~(size_t)255;
    return p;
  };
  uint16_t* xb    = (uint16_t*)alloc((size_t)T_TOK * D_DIM * 2);
  uint16_t* sfc1b = (uint16_t*)alloc((size_t)S_DIM * D_DIM * 2);
  uint16_t* sfc2b = (uint16_t*)alloc((size_t)S_DIM * D_DIM * 2);
  uint16_t* sfc3b = (uint16_t*)alloc((size_t)D_DIM * S_DIM * 2);
  uint16_t* w1b   = (uint16_t*)alloc((size_t)E_NUM * H_DIM * D_DIM * 2);
  uint16_t* w2b   = (uint16_t*)alloc((size_t)E_NUM * D_DIM * H_DIM * 2);
  uint16_t* hsb   = (uint16_t*)alloc((size_t)T_TOK * S_DIM * 2);
  uint16_t* hbuf  = (uint16_t*)alloc((size_t)2 * T_TOK * H_DIM * 2);
  float* slot_out = (float*)alloc((size_t)2 * T_TOK * D_DIM * 4);
  int*   top_idx  = (int*)alloc((size_t)T_TOK * 2 * 4);
  float* top_w    = (float*)alloc((size_t)T_TOK * 2 * 4);
  int*   counts   = (int*)alloc(E_NUM * 4);
  int*   offsets  = (int*)alloc((E_NUM + 1) * 4);
  int*   cursor   = (int*)alloc(E_NUM * 4);
  int*   slot_token = (int*)alloc((size_t)2 * T_TOK * 4);
  float* slot_w   = (float*)alloc((size_t)2 * T_TOK * 4);
  int*   slot_of  = (int*)alloc((size_t)2 * T_TOK * 4);

  // 1. casts
  {
    int n4;
    n4 = T_TOK * D_DIM / 4;  k_cast<<<(n4 + 255) / 256, 256, 0, stream>>>(x, xb, n4);
    n4 = S_DIM * D_DIM / 4;  k_cast<<<(n4 + 255) / 256, 256, 0, stream>>>(sfc1, sfc1b, n4);
    n4 = S_DIM * D_DIM / 4;  k_cast<<<(n4 + 255) / 256, 256, 0, stream>>>(sfc2, sfc2b, n4);
    n4 = D_DIM * S_DIM / 4;  k_cast<<<(n4 + 255) / 256, 256, 0, stream>>>(sfc3, sfc3b, n4);
    n4 = E_NUM * H_DIM * D_DIM / 4; k_cast<<<(n4 + 255) / 256, 256, 0, stream>>>(w1, w1b, n4);
    n4 = E_NUM * D_DIM * H_DIM / 4; k_cast<<<(n4 + 255) / 256, 256, 0, stream>>>(w2, w2b, n4);
  }
  // 2. router
  k_zero_counts<<<1, 64, 0, stream>>>(counts);
  k_router<<<T_TOK / 4, 256, 0, stream>>>(x, gatew, top_idx, top_w, counts);
  k_offsets<<<1, 64, 0, stream>>>(counts, offsets, cursor);
  k_fill<<<(2 * T_TOK + 255) / 256, 256, 0, stream>>>(top_idx, top_w, cursor, slot_token, slot_w, slot_of);
  // 3. shared expert
  k_dual_gemm_silu<<<dim3(T_TOK / 128, S_DIM / 128), 256, 0, stream>>>(xb, sfc1b, sfc2b, hsb);
  k_gemm_shared_out<<<dim3(T_TOK / 128, D_DIM / 128), 256, 0, stream>>>(hsb, sfc3b, out);
  // 4. MoE grouped
  k_moe1<<<dim3(T_TOK / 128, H_DIM / 128, E_NUM), 256, 0, stream>>>(xb, w1b, offsets, slot_token, hbuf);
  k_moe2<<<dim3(T_TOK / 128, D_DIM / 128, E_NUM), 256, 0, stream>>>(hbuf, w2b, offsets, slot_token, slot_w, slot_out);
  // 5. combine MoE slots into output
  k_combine<<<T_TOK, 256, 0, stream>>>(slot_out, slot_of, out);
}